// Round 1
// baseline (4159.094 us; speedup 1.0000x reference)
//
#include <hip/hip_runtime.h>

#define NODES 2047
#define GD 1280
#define DD 256

__device__ __forceinline__ float sigf(float x) {
    return 1.0f / (1.0f + __expf(-x));
}
__device__ __forceinline__ float tanhf_fast(float x) {
    float ax = fabsf(x);
    float t = __expf(-2.0f * ax);
    float r = (1.0f - t) / (1.0f + t);
    return x < 0.0f ? -r : r;
}

// One tree level (or the leaf level) as a fused GEMM + LSTM-cell epilogue.
// A: (M, K) rows are either gathered emb rows (L0, K=300) or contiguous
//    [h_l|h_r] pairs from h_all (tree, K=512).
// B: gate-plane g of the weight matrix = columns [g*256, (g+1)*256) of
//    Wx (L0) or of [Ul;Ur] (tree, k<256 -> Ul, else Ur).
// Block: 64 rows x 32 d-dims (=160 gate columns). 256 threads:
//    tx in [0,16) -> 2 d's each; ty in [0,16) -> 4 rows each.
template<bool IS_L0>
__global__ __launch_bounds__(256)
void level_kernel(const float* __restrict__ Asrc,   // emb_table (L0) or h_all
                  const int*   __restrict__ wids,   // L0 only
                  const float* __restrict__ W0,     // Wx (L0) or Ul
                  const float* __restrict__ W1,     // Ur (tree only)
                  const float* __restrict__ bias,   // (1280,)
                  const float* __restrict__ c_in,   // (B, 2*n_out, 256), tree only
                  float*       __restrict__ h_all,  // (B, 2047, 256)
                  float*       __restrict__ c_out,  // (B, n_out, 256)
                  int n_out, int off_out, int off_prev, int log2n)
{
    const int K = IS_L0 ? 300 : 512;
    __shared__ float As[16][68];        // [k][row], padded to kill xpose-store conflicts
    __shared__ float Bs[5][16][32];     // [gate][k][d]

    int tid = threadIdx.x;
    int tx = tid & 15;
    int ty = tid >> 4;
    int row0 = blockIdx.x * 64;
    int d0 = blockIdx.y * 32;

    float acc[4][10];
    #pragma unroll
    for (int r = 0; r < 4; r++)
        #pragma unroll
        for (int c = 0; c < 10; c++) acc[r][c] = 0.0f;

    // per-thread A staging address (row fixed across K loop)
    int arow = tid >> 2;     // 64 rows
    int kv   = tid & 3;      // which float4 within BK=16
    long abase;
    if (IS_L0) {
        int wid = wids[row0 + arow];
        abase = (long)wid * 300;
    } else {
        int rg = row0 + arow;
        int b = rg >> log2n;
        int j = rg & (n_out - 1);
        abase = ((long)(b * NODES + off_prev)) * DD + (long)j * 512;
    }

    for (int k0 = 0; k0 < K; k0 += 16) {
        // ---- stage A tile (64x16), transposed into As[k][row] ----
        {
            int k = k0 + kv * 4;
            float4 v;
            if (!IS_L0 || k0 + 16 <= K) {
                v = *(const float4*)(Asrc + abase + k);
            } else {
                v.x = (k + 0 < K) ? Asrc[abase + k + 0] : 0.0f;
                v.y = (k + 1 < K) ? Asrc[abase + k + 1] : 0.0f;
                v.z = (k + 2 < K) ? Asrc[abase + k + 2] : 0.0f;
                v.w = (k + 3 < K) ? Asrc[abase + k + 3] : 0.0f;
            }
            As[kv * 4 + 0][arow] = v.x;
            As[kv * 4 + 1][arow] = v.y;
            As[kv * 4 + 2][arow] = v.z;
            As[kv * 4 + 3][arow] = v.w;
        }
        // ---- stage B tile: 5 planes x 16k x 32d = 2560 floats, 10/thread ----
        #pragma unroll
        for (int t = 0; t < 10; t++) {
            int i = tid + t * 256;
            int dloc = i & 31;
            int k = (i >> 5) & 15;
            int g = i >> 9;
            int kg = k0 + k;
            int col = g * 256 + d0 + dloc;
            float val;
            if (IS_L0) {
                val = (kg < 300) ? W0[(long)kg * GD + col] : 0.0f;
            } else {
                val = (kg < 256) ? W0[(long)kg * GD + col]
                                 : W1[(long)(kg - 256) * GD + col];
            }
            Bs[g][k][dloc] = val;
        }
        __syncthreads();
        // ---- inner product ----
        #pragma unroll
        for (int kk = 0; kk < 16; kk++) {
            float4 a4 = *(const float4*)&As[kk][ty * 4];
            float av[4] = {a4.x, a4.y, a4.z, a4.w};
            #pragma unroll
            for (int g = 0; g < 5; g++) {
                float2 bv = *(const float2*)&Bs[g][kk][tx * 2];
                #pragma unroll
                for (int r = 0; r < 4; r++) {
                    acc[r][g * 2 + 0] += av[r] * bv.x;
                    acc[r][g * 2 + 1] += av[r] * bv.y;
                }
            }
        }
        __syncthreads();
    }

    // ---- fused LSTM cell epilogue ----
    float bi[10];
    #pragma unroll
    for (int g = 0; g < 5; g++) {
        bi[g * 2 + 0] = bias[g * 256 + d0 + tx * 2 + 0];
        bi[g * 2 + 1] = bias[g * 256 + d0 + tx * 2 + 1];
    }
    #pragma unroll
    for (int r = 0; r < 4; r++) {
        int rg = row0 + ty * 4 + r;
        int b = rg >> log2n;
        int j = rg & (n_out - 1);
        int node = off_out + j;
        long hbase = ((long)b * NODES + node) * DD;
        long cbase = ((long)b * n_out + j) * DD;
        #pragma unroll
        for (int dd = 0; dd < 2; dd++) {
            int d = d0 + tx * 2 + dd;
            float gi  = acc[r][0 + dd] + bi[0 + dd];
            float gfl = acc[r][2 + dd] + bi[2 + dd];
            float gfr = acc[r][4 + dd] + bi[4 + dd];
            float go  = acc[r][6 + dd] + bi[6 + dd];
            float gu  = acc[r][8 + dd] + bi[8 + dd];
            float c = sigf(gi) * tanhf_fast(gu);
            if (!IS_L0) {
                long cb = ((long)b * (2 * n_out) + 2 * j) * DD + d;
                c += sigf(gfl) * c_in[cb] + sigf(gfr) * c_in[cb + DD];
            }
            float h = sigf(go) * tanhf_fast(c);
            h_all[hbase + d] = h;
            c_out[cbase + d] = c;
        }
    }
}

// hidden (131008, 256) @ pred_W (256, 5) + pred_b. One wave per row.
__global__ __launch_bounds__(256)
void pred_kernel(const float* __restrict__ h_all,
                 const float* __restrict__ pW,
                 const float* __restrict__ pb,
                 float* __restrict__ out)
{
    __shared__ float Ws[DD * 5];
    int tid = threadIdx.x;
    for (int i = tid; i < DD * 5; i += 256) Ws[i] = pW[i];
    __syncthreads();
    int lane = tid & 63;
    int wave = tid >> 6;
    int row = blockIdx.x * 4 + wave;     // 131008 rows = 32752 * 4
    const float* hr = h_all + (long)row * DD;
    float a0 = 0.f, a1 = 0.f, a2 = 0.f, a3 = 0.f, a4 = 0.f;
    #pragma unroll
    for (int d0 = 0; d0 < DD; d0 += 64) {
        float hv = hr[d0 + lane];
        const float* w = &Ws[(d0 + lane) * 5];
        a0 += hv * w[0];
        a1 += hv * w[1];
        a2 += hv * w[2];
        a3 += hv * w[3];
        a4 += hv * w[4];
    }
    #pragma unroll
    for (int off = 32; off > 0; off >>= 1) {
        a0 += __shfl_down(a0, off);
        a1 += __shfl_down(a1, off);
        a2 += __shfl_down(a2, off);
        a3 += __shfl_down(a3, off);
        a4 += __shfl_down(a4, off);
    }
    if (lane == 0) {
        long ob = (long)row * 5;
        out[ob + 0] = a0 + pb[0];
        out[ob + 1] = a1 + pb[1];
        out[ob + 2] = a2 + pb[2];
        out[ob + 3] = a3 + pb[3];
        out[ob + 4] = a4 + pb[4];
    }
}

extern "C" void kernel_launch(void* const* d_in, const int* in_sizes, int n_in,
                              void* d_out, int out_size, void* d_ws, size_t ws_size,
                              hipStream_t stream)
{
    const int*   wids = (const int*)  d_in[0];
    const float* emb  = (const float*)d_in[1];
    const float* Wx   = (const float*)d_in[2];
    const float* Ul   = (const float*)d_in[3];
    const float* Ur   = (const float*)d_in[4];
    const float* bias = (const float*)d_in[5];
    const float* pW   = (const float*)d_in[6];
    const float* pb   = (const float*)d_in[7];
    float* out = (float*)d_out;

    // workspace: h_all (B,2047,256) + ping-pong c buffers
    float* h_all = (float*)d_ws;                        // 33,538,048 f
    float* c0 = h_all + (size_t)64 * NODES * DD;        // 16,777,216 f
    float* c1 = c0 + (size_t)64 * 1024 * DD;            //  8,388,608 f
    // total ~235 MB of d_ws

    // level 0 (leaves): gates = emb[ids] @ Wx + b, c_l = c_r = 0
    level_kernel<true><<<dim3(1024, 8), 256, 0, stream>>>(
        emb, wids, Wx, nullptr, bias, nullptr, h_all, c0,
        1024, 0, 0, 10);

    // tree levels 1..10
    for (int l = 1; l <= 10; l++) {
        int n_out = 1024 >> l;
        int off_out = 2048 - (2048 >> l);
        int off_prev = 2048 - (4096 >> l);
        float* cin  = (l & 1) ? c0 : c1;
        float* cout = (l & 1) ? c1 : c0;
        level_kernel<false><<<dim3(n_out, 8), 256, 0, stream>>>(
            h_all, nullptr, Ul, Ur, bias, cin, h_all, cout,
            n_out, off_out, off_prev, 10 - l);
    }

    // prediction head
    pred_kernel<<<32752, 256, 0, stream>>>(h_all, pW, pb, out);
}

// Round 2
// 643.644 us; speedup vs baseline: 6.4618x; 6.4618x over previous
//
#include <hip/hip_runtime.h>

#define NODES 2047
#define DD 256

typedef __attribute__((ext_vector_type(8))) __bf16 bf16x8;
typedef __attribute__((ext_vector_type(4))) float f32x4;

__device__ __forceinline__ float sigf(float x) { return 1.0f / (1.0f + __expf(-x)); }
__device__ __forceinline__ float tanhf_fast(float x) {
    float ax = fabsf(x);
    float t = __expf(-2.0f * ax);
    float r = (1.0f - t) / (1.0f + t);
    return x < 0.0f ? -r : r;
}
__device__ __forceinline__ ushort f2b(float x) {
    union { float f; uint u; } v; v.f = x;
    uint r = v.u + 0x7FFFu + ((v.u >> 16) & 1u);
    return (ushort)(r >> 16);
}
__device__ __forceinline__ float b2f(ushort b) {
    union { uint u; float f; } v; v.u = ((uint)b) << 16;
    return v.f;
}

#define GLD16(gp, lp) __builtin_amdgcn_global_load_lds( \
    (const __attribute__((address_space(1))) void*)(gp), \
    (__attribute__((address_space(3))) void*)(lp), 16, 0, 0)

// ---------- weight / embedding prep (fp32 -> bf16, transpose, pad) ----------
__global__ __launch_bounds__(256) void prep_emb(const float* __restrict__ emb,
                                                ushort* __restrict__ o) {
    long i = (long)blockIdx.x * 256 + threadIdx.x;   // [50000][320]
    if (i >= 50000L * 320) return;
    long v = i / 320;
    int k = (int)(i - v * 320);
    o[i] = f2b(k < 300 ? emb[v * 300 + k] : 0.0f);
}
__global__ __launch_bounds__(256) void prep_u(const float* __restrict__ Ul,
                                              const float* __restrict__ Ur,
                                              ushort* __restrict__ o) {
    int i = blockIdx.x * 256 + threadIdx.x;          // U_t[1280][512]
    if (i >= 1280 * 512) return;
    int c = i >> 9, k = i & 511;
    o[i] = f2b(k < 256 ? Ul[k * 1280 + c] : Ur[(k - 256) * 1280 + c]);
}
__global__ __launch_bounds__(256) void prep_wx(const float* __restrict__ Wx,
                                               ushort* __restrict__ o) {
    int i = blockIdx.x * 256 + threadIdx.x;          // WxT[1280][320]
    if (i >= 1280 * 320) return;
    int c = i / 320, k = i - c * 320;
    o[i] = f2b(k < 300 ? Wx[k * 1280 + c] : 0.0f);
}

// ---------- fused level GEMM (bf16 MFMA) + LSTM cell epilogue ----------
// Block tile: 128 rows x (5 gates x 32 d). 4 waves as 2x2 (wave: 64 rows x 80 cols).
// A_lds: 8 fm-blocks, slot l <-> (kg=l>>4, row=fmb*16+(l&15)), 16B each -> linear lane order.
// B_lds: 10 cg-blocks (col-major weight slices), same slot scheme.
template<bool IS_L0>
__global__ __launch_bounds__(256)
void level_mfma(const ushort* __restrict__ Asrc,   // embb (L0) or h_all bf16
                const int*    __restrict__ wids,   // L0 only
                const ushort* __restrict__ Bt,     // [1280][KF] bf16 (col-major weights)
                const float*  __restrict__ bias,   // (1280,)
                const float*  __restrict__ c_in,   // (B, 2n, 256) fp32, tree only
                ushort*       __restrict__ h_all,  // (B, 2047, 256) bf16
                float*        __restrict__ c_out,  // (B, n, 256) fp32
                int M, int n_out, int off_out, int off_prev, int log2n)
{
    constexpr int KF = IS_L0 ? 320 : 512;
    __shared__ bf16x8 A_lds[8 * 64];    // 8 KB
    __shared__ bf16x8 B_lds[10 * 64];   // 10 KB

    const int tid = threadIdx.x;
    const int l   = tid & 63;
    const int w   = tid >> 6;
    const int wr  = w >> 1;
    const int wc  = w & 1;
    const int row0 = blockIdx.x * 128;
    const int d0   = blockIdx.y * 32;
    const int l15  = l & 15;
    const int kg   = l >> 4;

    // per-lane global source pointers for A (2 fm-blocks per wave)
    const ushort* aptr[2];
    #pragma unroll
    for (int t = 0; t < 2; t++) {
        int fmb = 2 * w + t;
        int rg = row0 + fmb * 16 + l15;
        if (rg >= M) rg = 0;                       // clamp (stores predicated)
        long rb;
        if (IS_L0) {
            rb = (long)wids[rg] * 320;
        } else {
            int b = rg >> log2n;
            int j = rg & (n_out - 1);
            rb = ((long)(b * NODES + off_prev)) * DD + (long)j * 512;
        }
        aptr[t] = Asrc + rb + kg * 8;
    }
    // per-lane global source pointers for B (cg = w, w+4, w+8)
    const ushort* bptr[3];
    #pragma unroll
    for (int t = 0; t < 3; t++) {
        int cg = w + 4 * t;
        if (cg >= 10) cg = w;                      // dummy, unused
        int cl = cg * 16 + l15;
        int g = cl >> 5, ds = cl & 31;
        int gcol = g * 256 + d0 + ds;
        bptr[t] = Bt + (long)gcol * KF + kg * 8;
    }

    f32x4 acc[4][5];
    f32x4 zero = {0.0f, 0.0f, 0.0f, 0.0f};
    #pragma unroll
    for (int a = 0; a < 4; a++)
        #pragma unroll
        for (int g = 0; g < 5; g++) acc[a][g] = zero;

    for (int k0 = 0; k0 < KF; k0 += 32) {
        GLD16(aptr[0] + k0, &A_lds[(2 * w + 0) * 64]);
        GLD16(aptr[1] + k0, &A_lds[(2 * w + 1) * 64]);
        GLD16(bptr[0] + k0, &B_lds[w * 64]);
        GLD16(bptr[1] + k0, &B_lds[(w + 4) * 64]);
        if (w < 2) GLD16(bptr[2] + k0, &B_lds[(w + 8) * 64]);
        __syncthreads();

        bf16x8 af[4], bfr[5];
        #pragma unroll
        for (int fm = 0; fm < 4; fm++) af[fm] = A_lds[(wr * 4 + fm) * 64 + l];
        #pragma unroll
        for (int g = 0; g < 5; g++) bfr[g] = B_lds[(g * 2 + wc) * 64 + l];
        #pragma unroll
        for (int fm = 0; fm < 4; fm++)
            #pragma unroll
            for (int g = 0; g < 5; g++)
                acc[fm][g] = __builtin_amdgcn_mfma_f32_16x16x32_bf16(
                    af[fm], bfr[g], acc[fm][g], 0, 0, 0);
        __syncthreads();
    }

    // ---- fused LSTM cell epilogue ----
    const int d = d0 + wc * 16 + l15;
    float bi[5];
    #pragma unroll
    for (int g = 0; g < 5; g++) bi[g] = bias[g * 256 + d];

    #pragma unroll
    for (int fm = 0; fm < 4; fm++) {
        #pragma unroll
        for (int j = 0; j < 4; j++) {
            int rg = row0 + wr * 64 + fm * 16 + kg * 4 + j;   // D: m=(l>>4)*4+j
            if (rg < M) {
                int b = rg >> log2n;
                int jj = rg & (n_out - 1);
                float gi  = acc[fm][0][j] + bi[0];
                float gfl = acc[fm][1][j] + bi[1];
                float gfr = acc[fm][2][j] + bi[2];
                float go  = acc[fm][3][j] + bi[3];
                float gu  = acc[fm][4][j] + bi[4];
                float c = sigf(gi) * tanhf_fast(gu);
                if (!IS_L0) {
                    long cb = ((long)b * (2 * n_out) + 2 * jj) * DD + d;
                    c += sigf(gfl) * c_in[cb] + sigf(gfr) * c_in[cb + DD];
                }
                float h = sigf(go) * tanhf_fast(c);
                h_all[((long)b * NODES + (off_out + jj)) * DD + d] = f2b(h);
                c_out[((long)b * n_out + jj) * DD + d] = c;
            }
        }
    }
}

// ---------- prediction head: (131008, 256) bf16 @ (256,5) + b ----------
__global__ __launch_bounds__(256)
void pred_kernel(const ushort* __restrict__ h_all, const float* __restrict__ pW,
                 const float* __restrict__ pb, float* __restrict__ out)
{
    int tid = threadIdx.x;
    int lane = tid & 63, wave = tid >> 6;
    long row = (long)blockIdx.x * 4 + wave;      // 131008 = 32752*4
    const ushort* hr = h_all + row * DD;
    float a[5] = {0.f, 0.f, 0.f, 0.f, 0.f};
    #pragma unroll
    for (int q = 0; q < 4; q++) {
        int dd = lane + q * 64;
        float x = b2f(hr[dd]);
        #pragma unroll
        for (int g = 0; g < 5; g++) a[g] += x * pW[dd * 5 + g];
    }
    #pragma unroll
    for (int off = 32; off > 0; off >>= 1) {
        #pragma unroll
        for (int g = 0; g < 5; g++) a[g] += __shfl_down(a[g], off);
    }
    if (lane == 0) {
        #pragma unroll
        for (int g = 0; g < 5; g++) out[row * 5 + g] = a[g] + pb[g];
    }
}

extern "C" void kernel_launch(void* const* d_in, const int* in_sizes, int n_in,
                              void* d_out, int out_size, void* d_ws, size_t ws_size,
                              hipStream_t stream)
{
    const int*   wids = (const int*)  d_in[0];
    const float* emb  = (const float*)d_in[1];
    const float* Wx   = (const float*)d_in[2];
    const float* Ul   = (const float*)d_in[3];
    const float* Ur   = (const float*)d_in[4];
    const float* bias = (const float*)d_in[5];
    const float* pW   = (const float*)d_in[6];
    const float* pb   = (const float*)d_in[7];
    float* out = (float*)d_out;

    char* ws = (char*)d_ws;
    ushort* embb = (ushort*)ws;  ws += (size_t)50000 * 320 * 2;       // 32.0 MB
    ushort* Ut   = (ushort*)ws;  ws += (size_t)1280 * 512 * 2;        //  1.3 MB
    ushort* WxT  = (ushort*)ws;  ws += (size_t)1280 * 320 * 2;        //  0.8 MB
    ushort* h_all= (ushort*)ws;  ws += (size_t)64 * NODES * DD * 2;   // 67.0 MB
    float*  c0   = (float*)ws;   ws += (size_t)64 * 1024 * DD * 4;    // 67.1 MB
    float*  c1   = (float*)ws;                                        // 33.5 MB

    prep_emb<<<(50000 * 320 + 255) / 256, 256, 0, stream>>>(emb, embb);
    prep_u<<<(1280 * 512 + 255) / 256, 256, 0, stream>>>(Ul, Ur, Ut);
    prep_wx<<<(1280 * 320 + 255) / 256, 256, 0, stream>>>(Wx, WxT);

    // level 0: gates = emb_bf16[ids] @ WxT^T, c_l = c_r = 0
    level_mfma<true><<<dim3(512, 8), 256, 0, stream>>>(
        embb, wids, WxT, bias, nullptr, h_all, c0, 65536, 1024, 0, 0, 10);

    // tree levels 1..10
    for (int lvl = 1; lvl <= 10; lvl++) {
        int n = 1024 >> lvl;
        int M = 64 * n;
        int off_out = 2048 - (2048 >> lvl);
        int off_prev = 2048 - (4096 >> lvl);
        float* cin  = (lvl & 1) ? c0 : c1;
        float* cout = (lvl & 1) ? c1 : c0;
        level_mfma<false><<<dim3((M + 127) / 128, 8), 256, 0, stream>>>(
            h_all, nullptr, Ut, bias, cin, h_all, cout,
            M, n, off_out, off_prev, 10 - lvl);
    }

    pred_kernel<<<32752, 256, 0, stream>>>(h_all, pW, pb, out);
}